// Round 1
// baseline (630.157 us; speedup 1.0000x reference)
//
#include <hip/hip_runtime.h>

typedef __attribute__((ext_vector_type(8))) short short8;
typedef __attribute__((ext_vector_type(4))) float float4_t;
typedef __attribute__((ext_vector_type(4))) unsigned short ushort4_t;

#define NR 8192
#define C 128
#define SPLITK 8
#define KCHUNK (NR / SPLITK)   // 1024

// Static device scratch (avoids depending on ws_size; fully rewritten each call).
__device__ unsigned short g_xbT[(size_t)C * NR];    // xbT[c][n] = bf16(x[n][c])
__device__ unsigned short g_T1b[(size_t)NR * C];    // row-major bf16 T1
__device__ unsigned short g_T1bT[(size_t)C * NR];   // T1bT[c][n] = bf16(T1[n][c])
__device__ unsigned short g_Wb[3 * C * C];          // bf16 W, same layout as W
__device__ float g_part[(size_t)SPLITK * NR * C];   // split-K partials (32 MB)

__device__ __forceinline__ unsigned short f2bf(float f) {
  union { float f; unsigned u; } v; v.f = f;
  unsigned r = v.u + 0x7fffu + ((v.u >> 16) & 1u);  // RNE
  return (unsigned short)(r >> 16);
}

// ---- tiny: W fp32 -> bf16 (3*128*128 = 49152 elems) -------------------------
__global__ void cvt_w(const float* __restrict__ W) {
  int i = (blockIdx.x * 256 + threadIdx.x) * 4;
  float4_t v = *(const float4_t*)(W + i);
  ushort4_t h; h[0]=f2bf(v[0]); h[1]=f2bf(v[1]); h[2]=f2bf(v[2]); h[3]=f2bf(v[3]);
  *(ushort4_t*)(g_Wb + i) = h;
}

// ---- x [8192][128] fp32 -> xbT [128][8192] bf16 (tiled transpose) -----------
__global__ void transpose_x(const float* __restrict__ x) {
  __shared__ unsigned short xt[64][72];   // 72: rows stay 16B aligned
  int r0 = blockIdx.x * 64;
  int c0 = blockIdx.y * 64;
  int t = threadIdx.x;
  int rr = t >> 4;            // 0..15
  int cc = (t & 15) * 4;      // 0,4,...,60
#pragma unroll
  for (int i = 0; i < 4; i++) {
    int row = i * 16 + rr;
    float4_t v = *(const float4_t*)(x + (size_t)(r0 + row) * C + c0 + cc);
    ushort4_t h; h[0]=f2bf(v[0]); h[1]=f2bf(v[1]); h[2]=f2bf(v[2]); h[3]=f2bf(v[3]);
    *(ushort4_t*)(&xt[row][cc]) = h;
  }
  __syncthreads();
  int c = t >> 2;             // 0..63
  int q = t & 3;              // 0..3
  unsigned short* dst = g_xbT + (size_t)(c0 + c) * NR + r0 + q * 16;
#pragma unroll
  for (int seg = 0; seg < 4; seg++) {
    ushort4_t h;
#pragma unroll
    for (int j = 0; j < 4; j++) h[j] = xt[q * 16 + seg * 4 + j][c];
    *(ushort4_t*)(dst + seg * 4) = h;
  }
}

// ---- big GEMM: part[s] = L[:, sK:(s+1)K] @ B-chunk, no LDS, bf16 MFMA -------
// which==0: B^T = g_xbT (computes T1 partials); which==1: B^T = g_T1bT (U partials)
__global__ __launch_bounds__(256, 2) void big_gemm(const float* __restrict__ L, int which) {
  const unsigned short* __restrict__ BT = which ? g_T1bT : g_xbT;
  int tid = threadIdx.x;
  int wave = tid >> 6;
  int lane = tid & 63;
  int l15 = lane & 15, lq = lane >> 4;
  int m0 = blockIdx.x * 128 + wave * 32;       // wave covers 32 rows
  int kb = blockIdx.y * KCHUNK;

  const float* pa0 = L + (size_t)(m0 + l15) * NR + kb + lq * 8;
  const float* pa1 = pa0 + (size_t)16 * NR;
  const unsigned short* pb = BT + (size_t)l15 * NR + kb + lq * 8;

  float4_t acc[2][8];
#pragma unroll
  for (int mi = 0; mi < 2; mi++)
#pragma unroll
    for (int ni = 0; ni < 8; ni++) acc[mi][ni] = (float4_t){0.f, 0.f, 0.f, 0.f};

  for (int kk = 0; kk < KCHUNK; kk += 32) {
    short8 bfr[8];
#pragma unroll
    for (int ni = 0; ni < 8; ni++)
      bfr[ni] = *(const short8*)(pb + (size_t)ni * 16 * NR + kk);
    short8 afr[2];
#pragma unroll
    for (int mi = 0; mi < 2; mi++) {
      const float* pa = (mi ? pa1 : pa0) + kk;
      float4_t f0 = *(const float4_t*)pa;
      float4_t f1 = *(const float4_t*)(pa + 4);
      short8 a;
      a[0]=(short)f2bf(f0[0]); a[1]=(short)f2bf(f0[1]); a[2]=(short)f2bf(f0[2]); a[3]=(short)f2bf(f0[3]);
      a[4]=(short)f2bf(f1[0]); a[5]=(short)f2bf(f1[1]); a[6]=(short)f2bf(f1[2]); a[7]=(short)f2bf(f1[3]);
      afr[mi] = a;
    }
#pragma unroll
    for (int ni = 0; ni < 8; ni++)
#pragma unroll
      for (int mi = 0; mi < 2; mi++)
        acc[mi][ni] = __builtin_amdgcn_mfma_f32_16x16x32_bf16(afr[mi], bfr[ni], acc[mi][ni], 0, 0, 0);
  }

  float* po = g_part + (size_t)blockIdx.y * NR * C;
#pragma unroll
  for (int mi = 0; mi < 2; mi++)
#pragma unroll
    for (int ni = 0; ni < 8; ni++)
#pragma unroll
      for (int r = 0; r < 4; r++)
        po[(size_t)(m0 + mi * 16 + lq * 4 + r) * C + ni * 16 + l15] = acc[mi][ni][r];
}

// ---- reduce split-K partials -> T1 bf16 (row-major + transposed) ------------
__global__ void reduce_t1() {
  __shared__ unsigned short tile[32][132];   // rows 264B -> 8B-aligned ushort4 ok
  int r0 = blockIdx.x * 32;
  int t = threadIdx.x;
#pragma unroll
  for (int e = 0; e < 4; e++) {
    int linear = e * 1024 + t * 4;
    int r = linear >> 7, c = linear & 127;
    float4_t s = (float4_t){0.f, 0.f, 0.f, 0.f};
#pragma unroll
    for (int p = 0; p < SPLITK; p++)
      s += *(const float4_t*)(g_part + (size_t)p * NR * C + (size_t)(r0 + r) * C + c);
    ushort4_t h; h[0]=f2bf(s[0]); h[1]=f2bf(s[1]); h[2]=f2bf(s[2]); h[3]=f2bf(s[3]);
    *(ushort4_t*)(g_T1b + (size_t)(r0 + r) * C + c) = h;
    *(ushort4_t*)(&tile[r][c]) = h;
  }
  __syncthreads();
  int c = t >> 1, half = t & 1;
  unsigned short* dst = g_T1bT + (size_t)c * NR + r0 + half * 16;
#pragma unroll
  for (int seg = 0; seg < 4; seg++) {
    ushort4_t h;
#pragma unroll
    for (int j = 0; j < 4; j++) h[j] = tile[half * 16 + seg * 4 + j][c];
    *(ushort4_t*)(dst + seg * 4) = h;
  }
}

// ---- epilogue: reduce U partials, T2 = 2U - x, out = T0 W0^T + T1 W1^T + T2 W2^T
__global__ __launch_bounds__(256) void epilogue(const float* __restrict__ x,
                                                float* __restrict__ out) {
  __shared__ unsigned short t2[64][136];  // rows 272B -> 16B-aligned short8 ok
  int r0 = blockIdx.x * 64;
  int t = threadIdx.x;
#pragma unroll
  for (int e = 0; e < 8; e++) {
    int linear = e * 1024 + t * 4;
    int r = linear >> 7, c = linear & 127;
    float4_t s = (float4_t){0.f, 0.f, 0.f, 0.f};
#pragma unroll
    for (int p = 0; p < SPLITK; p++)
      s += *(const float4_t*)(g_part + (size_t)p * NR * C + (size_t)(r0 + r) * C + c);
    float4_t xv = *(const float4_t*)(x + (size_t)(r0 + r) * C + c);
    float4_t t2v = 2.0f * s - xv;
    ushort4_t h; h[0]=f2bf(t2v[0]); h[1]=f2bf(t2v[1]); h[2]=f2bf(t2v[2]); h[3]=f2bf(t2v[3]);
    *(ushort4_t*)(&t2[r][c]) = h;
  }
  __syncthreads();

  int wave = t >> 6, lane = t & 63, l15 = lane & 15, lq = lane >> 4;
  int m0 = r0 + wave * 16;
  float4_t acc[8];
#pragma unroll
  for (int ni = 0; ni < 8; ni++) acc[ni] = (float4_t){0.f, 0.f, 0.f, 0.f};

#pragma unroll
  for (int ks = 0; ks < 4; ks++) {
    int k0 = ks * 32 + lq * 8;
    const float* px = x + (size_t)(m0 + l15) * C + k0;
    float4_t f0 = *(const float4_t*)px;
    float4_t f1 = *(const float4_t*)(px + 4);
    short8 a0;
    a0[0]=(short)f2bf(f0[0]); a0[1]=(short)f2bf(f0[1]); a0[2]=(short)f2bf(f0[2]); a0[3]=(short)f2bf(f0[3]);
    a0[4]=(short)f2bf(f1[0]); a0[5]=(short)f2bf(f1[1]); a0[6]=(short)f2bf(f1[2]); a0[7]=(short)f2bf(f1[3]);
    short8 a1 = *(const short8*)(g_T1b + (size_t)(m0 + l15) * C + k0);
    short8 a2 = *(const short8*)(&t2[wave * 16 + l15][k0]);
#pragma unroll
    for (int ni = 0; ni < 8; ni++) {
      const unsigned short* pw = g_Wb + (size_t)(ni * 16 + l15) * C + k0;
      short8 w0 = *(const short8*)(pw);
      short8 w1 = *(const short8*)(pw + C * C);
      short8 w2 = *(const short8*)(pw + 2 * C * C);
      acc[ni] = __builtin_amdgcn_mfma_f32_16x16x32_bf16(a0, w0, acc[ni], 0, 0, 0);
      acc[ni] = __builtin_amdgcn_mfma_f32_16x16x32_bf16(a1, w1, acc[ni], 0, 0, 0);
      acc[ni] = __builtin_amdgcn_mfma_f32_16x16x32_bf16(a2, w2, acc[ni], 0, 0, 0);
    }
  }
#pragma unroll
  for (int ni = 0; ni < 8; ni++)
#pragma unroll
    for (int r = 0; r < 4; r++)
      out[(size_t)(m0 + lq * 4 + r) * C + ni * 16 + l15] = acc[ni][r];
}

extern "C" void kernel_launch(void* const* d_in, const int* in_sizes, int n_in,
                              void* d_out, int out_size, void* d_ws, size_t ws_size,
                              hipStream_t stream) {
  const float* x = (const float*)d_in[0];   // [8192][128]
  const float* L = (const float*)d_in[1];   // [8192][8192]
  const float* W = (const float*)d_in[2];   // [3][128][128]
  float* out = (float*)d_out;               // [8192][128]

  cvt_w<<<48, 256, 0, stream>>>(W);
  transpose_x<<<dim3(128, 2), 256, 0, stream>>>(x);
  big_gemm<<<dim3(64, SPLITK), 256, 0, stream>>>(L, 0);   // T1 partials
  reduce_t1<<<256, 256, 0, stream>>>();                   // -> T1b, T1bT
  big_gemm<<<dim3(64, SPLITK), 256, 0, stream>>>(L, 1);   // U = L@T1 partials
  epilogue<<<128, 256, 0, stream>>>(x, out);              // T2 + three W-GEMMs
}

// Round 2
// 559.128 us; speedup vs baseline: 1.1270x; 1.1270x over previous
//
#include <hip/hip_runtime.h>

typedef __attribute__((ext_vector_type(8))) short short8;
typedef __attribute__((ext_vector_type(4))) float float4_t;
typedef __attribute__((ext_vector_type(4))) unsigned short ushort4_t;

#define NR 8192
#define C 128
#define SPLITK 8
#define KCHUNK (NR / SPLITK)   // 1024
#define BK 64

// Static device scratch (fully rewritten each call; no reliance on ws_size).
__device__ unsigned short g_xbT[(size_t)C * NR];    // xbT[c][n] = bf16(x[n][c])
__device__ unsigned short g_T1b[(size_t)NR * C];    // row-major bf16 T1
__device__ unsigned short g_T1bT[(size_t)C * NR];   // T1bT[c][n] = bf16(T1[n][c])
__device__ unsigned short g_Wb[3 * C * C];          // bf16 W
__device__ unsigned short g_Lb[(size_t)NR * NR];    // bf16 L (134 MB, L3-resident)
__device__ float g_part[(size_t)SPLITK * NR * C];   // split-K partials (32 MB)

__device__ __forceinline__ unsigned short f2bf(float f) {
  union { float f; unsigned u; } v; v.f = f;
  unsigned r = v.u + 0x7fffu + ((v.u >> 16) & 1u);  // RNE
  return (unsigned short)(r >> 16);
}
__device__ __forceinline__ unsigned pk2(float a, float b) {
  union { float f; unsigned u; } x, y; x.f = a; y.f = b;
  unsigned ra = x.u + 0x7fffu + ((x.u >> 16) & 1u);
  unsigned rb = y.u + 0x7fffu + ((y.u >> 16) & 1u);
  return (ra >> 16) | (rb & 0xffff0000u);
}
__device__ __forceinline__ short8 cvt8(float4_t f0, float4_t f1) {
  union { unsigned u[4]; short8 s; } r;
  r.u[0] = pk2(f0[0], f0[1]); r.u[1] = pk2(f0[2], f0[3]);
  r.u[2] = pk2(f1[0], f1[1]); r.u[3] = pk2(f1[2], f1[3]);
  return r.s;
}

typedef __attribute__((address_space(3))) unsigned lds_uint;
typedef const __attribute__((address_space(1))) unsigned glob_uint;
__device__ __forceinline__ void gload_lds16(const void* g, void* l) {
  // async global->LDS, 16B/lane; LDS dest = wave-uniform base + lane*16
  __builtin_amdgcn_global_load_lds((glob_uint*)g, (lds_uint*)l, 16, 0, 0);
}

// ---- tiny: W fp32 -> bf16 ---------------------------------------------------
__global__ void cvt_w(const float* __restrict__ W) {
  int i = (blockIdx.x * 256 + threadIdx.x) * 4;
  float4_t v = *(const float4_t*)(W + i);
  ushort4_t h; h[0]=f2bf(v[0]); h[1]=f2bf(v[1]); h[2]=f2bf(v[2]); h[3]=f2bf(v[3]);
  *(ushort4_t*)(g_Wb + i) = h;
}

// ---- x [8192][128] fp32 -> xbT [128][8192] bf16 -----------------------------
__global__ void transpose_x(const float* __restrict__ x) {
  __shared__ unsigned short xt[64][72];
  int r0 = blockIdx.x * 64;
  int c0 = blockIdx.y * 64;
  int t = threadIdx.x;
  int rr = t >> 4;
  int cc = (t & 15) * 4;
#pragma unroll
  for (int i = 0; i < 4; i++) {
    int row = i * 16 + rr;
    float4_t v = *(const float4_t*)(x + (size_t)(r0 + row) * C + c0 + cc);
    ushort4_t h; h[0]=f2bf(v[0]); h[1]=f2bf(v[1]); h[2]=f2bf(v[2]); h[3]=f2bf(v[3]);
    *(ushort4_t*)(&xt[row][cc]) = h;
  }
  __syncthreads();
  int c = t >> 2;
  int q = t & 3;
  unsigned short* dst = g_xbT + (size_t)(c0 + c) * NR + r0 + q * 16;
#pragma unroll
  for (int seg = 0; seg < 4; seg++) {
    ushort4_t h;
#pragma unroll
    for (int j = 0; j < 4; j++) h[j] = xt[q * 16 + seg * 4 + j][c];
    *(ushort4_t*)(dst + seg * 4) = h;
  }
}

// ---- GEMM1: part = L(fp32) @ x ; also writes back bf16 L --------------------
// LDS-staged (global_load_lds w=16), XOR-swizzled 16B units (<=2-way bank alias)
__global__ __launch_bounds__(256, 2) void gemm1(const float* __restrict__ L) {
  __shared__ __attribute__((aligned(16))) float As[128 * BK];           // 32 KB
  __shared__ __attribute__((aligned(16))) unsigned short Bs[128 * BK];  // 16 KB
  int tid = threadIdx.x;
  int wave = tid >> 6, lane = tid & 63;
  int l15 = lane & 15, lq = lane >> 4;
  int m0 = blockIdx.x * 128;
  int kb = blockIdx.y * KCHUNK;

  // staging source pointers (lane-fixed; advance by BK each step)
  const float* pA[8];
#pragma unroll
  for (int i = 0; i < 8; i++) {
    int U = (wave * 8 + i) * 64 + lane;   // unit 0..2047
    int row = U >> 4, u = U & 15;
    pA[i] = L + (size_t)(m0 + row) * NR + kb + ((u ^ (row & 15)) << 2);
  }
  const unsigned short* pB[4];
#pragma unroll
  for (int i = 0; i < 4; i++) {
    int U = (wave * 4 + i) * 64 + lane;   // unit 0..1023
    int n = U >> 3, u = U & 7;
    pB[i] = g_xbT + (size_t)n * NR + kb + ((u ^ (n & 7)) << 3);
  }
  unsigned short* pW[2];
#pragma unroll
  for (int mi = 0; mi < 2; mi++)
    pW[mi] = g_Lb + (size_t)(m0 + wave * 32 + mi * 16 + l15) * NR + kb + lq * 8;

  float4_t acc[2][8];
#pragma unroll
  for (int mi = 0; mi < 2; mi++)
#pragma unroll
    for (int ni = 0; ni < 8; ni++) acc[mi][ni] = (float4_t){0.f, 0.f, 0.f, 0.f};

  for (int step = 0; step < KCHUNK / BK; step++) {
#pragma unroll
    for (int i = 0; i < 8; i++)
      gload_lds16(pA[i], (char*)As + (wave * 8 + i) * 1024);
#pragma unroll
    for (int i = 0; i < 4; i++)
      gload_lds16(pB[i], (char*)Bs + (wave * 4 + i) * 1024);
    __syncthreads();
#pragma unroll
    for (int ki = 0; ki < 2; ki++) {
      short8 b[8];
#pragma unroll
      for (int ni = 0; ni < 8; ni++) {
        int n = ni * 16 + l15;
        int u = ((ki << 2) | lq) ^ (n & 7);
        b[ni] = *(const short8*)((const char*)Bs + n * 128 + u * 16);
      }
#pragma unroll
      for (int mi = 0; mi < 2; mi++) {
        int row = wave * 32 + mi * 16 + l15;
        int u0 = ((ki << 3) | (lq << 1)) ^ (row & 15);
        float4_t f0 = *(const float4_t*)((const char*)As + row * 256 + u0 * 16);
        float4_t f1 = *(const float4_t*)((const char*)As + row * 256 + (u0 ^ 1) * 16);
        short8 a = cvt8(f0, f1);
        *(short8*)(pW[mi] + ki * 32) = a;   // bf16 L writeback
#pragma unroll
        for (int ni = 0; ni < 8; ni++)
          acc[mi][ni] = __builtin_amdgcn_mfma_f32_16x16x32_bf16(a, b[ni], acc[mi][ni], 0, 0, 0);
      }
    }
    __syncthreads();
#pragma unroll
    for (int i = 0; i < 8; i++) pA[i] += BK;
#pragma unroll
    for (int i = 0; i < 4; i++) pB[i] += BK;
    pW[0] += BK; pW[1] += BK;
  }

  float* po = g_part + (size_t)blockIdx.y * NR * C;
#pragma unroll
  for (int mi = 0; mi < 2; mi++)
#pragma unroll
    for (int ni = 0; ni < 8; ni++)
#pragma unroll
      for (int r = 0; r < 4; r++)
        po[(size_t)(m0 + wave * 32 + mi * 16 + lq * 4 + r) * C + ni * 16 + l15] = acc[mi][ni][r];
}

// ---- GEMM2: part = Lb(bf16) @ T1 --------------------------------------------
__global__ __launch_bounds__(256, 2) void gemm2() {
  __shared__ __attribute__((aligned(16))) unsigned short As[128 * BK];  // 16 KB
  __shared__ __attribute__((aligned(16))) unsigned short Bs[128 * BK];  // 16 KB
  int tid = threadIdx.x;
  int wave = tid >> 6, lane = tid & 63;
  int l15 = lane & 15, lq = lane >> 4;
  int m0 = blockIdx.x * 128;
  int kb = blockIdx.y * KCHUNK;

  const unsigned short* pA[4];
#pragma unroll
  for (int i = 0; i < 4; i++) {
    int U = (wave * 4 + i) * 64 + lane;
    int row = U >> 3, u = U & 7;
    pA[i] = g_Lb + (size_t)(m0 + row) * NR + kb + ((u ^ (row & 7)) << 3);
  }
  const unsigned short* pB[4];
#pragma unroll
  for (int i = 0; i < 4; i++) {
    int U = (wave * 4 + i) * 64 + lane;
    int n = U >> 3, u = U & 7;
    pB[i] = g_T1bT + (size_t)n * NR + kb + ((u ^ (n & 7)) << 3);
  }

  float4_t acc[2][8];
#pragma unroll
  for (int mi = 0; mi < 2; mi++)
#pragma unroll
    for (int ni = 0; ni < 8; ni++) acc[mi][ni] = (float4_t){0.f, 0.f, 0.f, 0.f};

  for (int step = 0; step < KCHUNK / BK; step++) {
#pragma unroll
    for (int i = 0; i < 4; i++)
      gload_lds16(pA[i], (char*)As + (wave * 4 + i) * 1024);
#pragma unroll
    for (int i = 0; i < 4; i++)
      gload_lds16(pB[i], (char*)Bs + (wave * 4 + i) * 1024);
    __syncthreads();
#pragma unroll
    for (int ki = 0; ki < 2; ki++) {
      short8 b[8];
#pragma unroll
      for (int ni = 0; ni < 8; ni++) {
        int n = ni * 16 + l15;
        int u = ((ki << 2) | lq) ^ (n & 7);
        b[ni] = *(const short8*)((const char*)Bs + n * 128 + u * 16);
      }
#pragma unroll
      for (int mi = 0; mi < 2; mi++) {
        int row = wave * 32 + mi * 16 + l15;
        int u = ((ki << 2) | lq) ^ (row & 7);
        short8 a = *(const short8*)((const char*)As + row * 128 + u * 16);
#pragma unroll
        for (int ni = 0; ni < 8; ni++)
          acc[mi][ni] = __builtin_amdgcn_mfma_f32_16x16x32_bf16(a, b[ni], acc[mi][ni], 0, 0, 0);
      }
    }
    __syncthreads();
#pragma unroll
    for (int i = 0; i < 4; i++) { pA[i] += BK; pB[i] += BK; }
  }

  float* po = g_part + (size_t)blockIdx.y * NR * C;
#pragma unroll
  for (int mi = 0; mi < 2; mi++)
#pragma unroll
    for (int ni = 0; ni < 8; ni++)
#pragma unroll
      for (int r = 0; r < 4; r++)
        po[(size_t)(m0 + wave * 32 + mi * 16 + lq * 4 + r) * C + ni * 16 + l15] = acc[mi][ni][r];
}

// ---- reduce split-K partials -> T1 bf16 (row-major + transposed) ------------
__global__ void reduce_t1() {
  __shared__ unsigned short tile[16][132];
  int r0 = blockIdx.x * 16;
  int t = threadIdx.x;
#pragma unroll
  for (int e = 0; e < 2; e++) {
    int linear = e * 1024 + t * 4;
    int r = linear >> 7, c = linear & 127;
    float4_t s = (float4_t){0.f, 0.f, 0.f, 0.f};
#pragma unroll
    for (int p = 0; p < SPLITK; p++)
      s += *(const float4_t*)(g_part + (size_t)p * NR * C + (size_t)(r0 + r) * C + c);
    ushort4_t h; h[0]=f2bf(s[0]); h[1]=f2bf(s[1]); h[2]=f2bf(s[2]); h[3]=f2bf(s[3]);
    *(ushort4_t*)(g_T1b + (size_t)(r0 + r) * C + c) = h;
    *(ushort4_t*)(&tile[r][c]) = h;
  }
  __syncthreads();
  int c = t >> 1, half = t & 1;
  unsigned short* dst = g_T1bT + (size_t)c * NR + r0 + half * 8;
#pragma unroll
  for (int seg = 0; seg < 2; seg++) {
    ushort4_t h;
#pragma unroll
    for (int j = 0; j < 4; j++) h[j] = tile[half * 8 + seg * 4 + j][c];
    *(ushort4_t*)(dst + seg * 4) = h;
  }
}

// ---- epilogue: reduce U partials, T2 = 2U - x, out = sum_j T_j W_j^T --------
__global__ __launch_bounds__(256) void epilogue(const float* __restrict__ x,
                                                float* __restrict__ out) {
  __shared__ unsigned short t2[32][136];
  int r0 = blockIdx.x * 32;
  int t = threadIdx.x;
#pragma unroll
  for (int e = 0; e < 4; e++) {
    int linear = e * 1024 + t * 4;
    int r = linear >> 7, c = linear & 127;
    float4_t s = (float4_t){0.f, 0.f, 0.f, 0.f};
#pragma unroll
    for (int p = 0; p < SPLITK; p++)
      s += *(const float4_t*)(g_part + (size_t)p * NR * C + (size_t)(r0 + r) * C + c);
    float4_t xv = *(const float4_t*)(x + (size_t)(r0 + r) * C + c);
    float4_t t2v = 2.0f * s - xv;
    ushort4_t h; h[0]=f2bf(t2v[0]); h[1]=f2bf(t2v[1]); h[2]=f2bf(t2v[2]); h[3]=f2bf(t2v[3]);
    *(ushort4_t*)(&t2[r][c]) = h;
  }
  __syncthreads();

  int wave = t >> 6, lane = t & 63, l15 = lane & 15, lq = lane >> 4;
  int mf = wave & 1, nh = wave >> 1;
  int m0r = r0 + mf * 16;
  float4_t acc[4];
#pragma unroll
  for (int ni = 0; ni < 4; ni++) acc[ni] = (float4_t){0.f, 0.f, 0.f, 0.f};

#pragma unroll
  for (int ks = 0; ks < 4; ks++) {
    int k0 = ks * 32 + lq * 8;
    const float* px = x + (size_t)(m0r + l15) * C + k0;
    float4_t f0 = *(const float4_t*)px;
    float4_t f1 = *(const float4_t*)(px + 4);
    short8 a0 = cvt8(f0, f1);
    short8 a1 = *(const short8*)(g_T1b + (size_t)(m0r + l15) * C + k0);
    short8 a2 = *(const short8*)(&t2[mf * 16 + l15][k0]);
#pragma unroll
    for (int ni = 0; ni < 4; ni++) {
      int n = nh * 64 + ni * 16 + l15;
      const unsigned short* pw = g_Wb + (size_t)n * C + k0;
      short8 w0 = *(const short8*)(pw);
      short8 w1 = *(const short8*)(pw + C * C);
      short8 w2 = *(const short8*)(pw + 2 * C * C);
      acc[ni] = __builtin_amdgcn_mfma_f32_16x16x32_bf16(a0, w0, acc[ni], 0, 0, 0);
      acc[ni] = __builtin_amdgcn_mfma_f32_16x16x32_bf16(a1, w1, acc[ni], 0, 0, 0);
      acc[ni] = __builtin_amdgcn_mfma_f32_16x16x32_bf16(a2, w2, acc[ni], 0, 0, 0);
    }
  }
#pragma unroll
  for (int ni = 0; ni < 4; ni++)
#pragma unroll
    for (int r = 0; r < 4; r++)
      out[(size_t)(m0r + lq * 4 + r) * C + nh * 64 + ni * 16 + l15] = acc[ni][r];
}

extern "C" void kernel_launch(void* const* d_in, const int* in_sizes, int n_in,
                              void* d_out, int out_size, void* d_ws, size_t ws_size,
                              hipStream_t stream) {
  const float* x = (const float*)d_in[0];   // [8192][128]
  const float* L = (const float*)d_in[1];   // [8192][8192]
  const float* W = (const float*)d_in[2];   // [3][128][128]
  float* out = (float*)d_out;               // [8192][128]

  cvt_w<<<48, 256, 0, stream>>>(W);
  transpose_x<<<dim3(128, 2), 256, 0, stream>>>(x);
  gemm1<<<dim3(64, SPLITK), 256, 0, stream>>>(L);   // T1 partials + bf16 L
  reduce_t1<<<512, 256, 0, stream>>>();             // -> T1b, T1bT
  gemm2<<<dim3(64, SPLITK), 256, 0, stream>>>();    // U = Lb @ T1 partials
  epilogue<<<256, 256, 0, stream>>>(x, out);        // T2 + three W-GEMMs
}

// Round 3
// 509.457 us; speedup vs baseline: 1.2369x; 1.0975x over previous
//
#include <hip/hip_runtime.h>

typedef __attribute__((ext_vector_type(8))) short short8;
typedef __attribute__((ext_vector_type(4))) float float4_t;
typedef __attribute__((ext_vector_type(4))) unsigned short ushort4_t;

#define NR 8192
#define C 128
#define SPLITK 8
#define KCHUNK (NR / SPLITK)   // 1024
#define BK 64

// Static device scratch (fully rewritten each call; no reliance on ws_size).
__device__ unsigned short g_xbT[(size_t)C * NR];    // xbT[c][n] = bf16(x[n][c])
__device__ unsigned short g_T1b[(size_t)NR * C];    // row-major bf16 T1
__device__ unsigned short g_T1bT[(size_t)C * NR];   // T1bT[c][n] = bf16(T1[n][c])
__device__ unsigned short g_Wb[3 * C * C];          // bf16 W
__device__ unsigned short g_Lb[(size_t)NR * NR];    // bf16 L (134 MB)
__device__ float g_part[(size_t)SPLITK * NR * C];   // split-K partials (32 MB)

__device__ __forceinline__ unsigned short f2bf(float f) {
  union { float f; unsigned u; } v; v.f = f;
  unsigned r = v.u + 0x7fffu + ((v.u >> 16) & 1u);  // RNE
  return (unsigned short)(r >> 16);
}
__device__ __forceinline__ unsigned pk2(float a, float b) {
  union { float f; unsigned u; } x, y; x.f = a; y.f = b;
  unsigned ra = x.u + 0x7fffu + ((x.u >> 16) & 1u);
  unsigned rb = y.u + 0x7fffu + ((y.u >> 16) & 1u);
  return (ra >> 16) | (rb & 0xffff0000u);
}
__device__ __forceinline__ short8 cvt8(float4_t f0, float4_t f1) {
  union { unsigned u[4]; short8 s; } r;
  r.u[0] = pk2(f0[0], f0[1]); r.u[1] = pk2(f0[2], f0[3]);
  r.u[2] = pk2(f1[0], f1[1]); r.u[3] = pk2(f1[2], f1[3]);
  return r.s;
}

typedef __attribute__((address_space(3))) unsigned lds_uint;
typedef const __attribute__((address_space(1))) unsigned glob_uint;
__device__ __forceinline__ void gload_lds16(const void* g, void* l) {
  __builtin_amdgcn_global_load_lds((glob_uint*)g, (lds_uint*)l, 16, 0, 0);
}

// ---- tiny: W fp32 -> bf16 ---------------------------------------------------
__global__ void cvt_w(const float* __restrict__ W) {
  int i = (blockIdx.x * 256 + threadIdx.x) * 4;
  float4_t v = *(const float4_t*)(W + i);
  ushort4_t h; h[0]=f2bf(v[0]); h[1]=f2bf(v[1]); h[2]=f2bf(v[2]); h[3]=f2bf(v[3]);
  *(ushort4_t*)(g_Wb + i) = h;
}

// ---- streaming L fp32 -> bf16 (fully coalesced, latency-insensitive) --------
__global__ __launch_bounds__(256) void cvt_L(const float* __restrict__ L) {
  size_t i = ((size_t)blockIdx.x * 256 + threadIdx.x) * 8;
  float4_t f0 = *(const float4_t*)(L + i);
  float4_t f1 = *(const float4_t*)(L + i + 4);
  *(short8*)(g_Lb + i) = cvt8(f0, f1);
}

// ---- x [8192][128] fp32 -> xbT [128][8192] bf16 -----------------------------
__global__ void transpose_x(const float* __restrict__ x) {
  __shared__ unsigned short xt[64][72];
  int r0 = blockIdx.x * 64;
  int c0 = blockIdx.y * 64;
  int t = threadIdx.x;
  int rr = t >> 4;
  int cc = (t & 15) * 4;
#pragma unroll
  for (int i = 0; i < 4; i++) {
    int row = i * 16 + rr;
    float4_t v = *(const float4_t*)(x + (size_t)(r0 + row) * C + c0 + cc);
    ushort4_t h; h[0]=f2bf(v[0]); h[1]=f2bf(v[1]); h[2]=f2bf(v[2]); h[3]=f2bf(v[3]);
    *(ushort4_t*)(&xt[row][cc]) = h;
  }
  __syncthreads();
  int c = t >> 2;
  int q = t & 3;
  unsigned short* dst = g_xbT + (size_t)(c0 + c) * NR + r0 + q * 16;
#pragma unroll
  for (int seg = 0; seg < 4; seg++) {
    ushort4_t h;
#pragma unroll
    for (int j = 0; j < 4; j++) h[j] = xt[q * 16 + seg * 4 + j][c];
    *(ushort4_t*)(dst + seg * 4) = h;
  }
}

// ---- bf16 GEMM: part = Lb @ B ; BM=64, BN=128, BK=64, 4 blocks/CU -----------
// which==0: BT = g_xbT (T1 partials); which==1: BT = g_T1bT (U partials)
__global__ __launch_bounds__(256, 4) void gemm_bf16(int which) {
  const unsigned short* __restrict__ BT = which ? g_T1bT : g_xbT;
  __shared__ __attribute__((aligned(16))) unsigned short As[64 * BK];   // 8 KB
  __shared__ __attribute__((aligned(16))) unsigned short Bs[128 * BK];  // 16 KB
  int tid = threadIdx.x;
  int wave = tid >> 6, lane = tid & 63;
  int l15 = lane & 15, lq = lane >> 4;
  int m0 = blockIdx.x * 64;
  int kb = blockIdx.y * KCHUNK;

  // staging source pointers: lane-fixed, advance by BK each step.
  // LDS dest is linear (unit U = row*8 + p); source k-offset is XOR-swizzled
  // so logical unit u lands at physical p = u ^ (row&7).
  const unsigned short* pA[2];
#pragma unroll
  for (int i = 0; i < 2; i++) {
    int U = (wave * 2 + i) * 64 + lane;   // 0..511
    int row = U >> 3, p = U & 7;
    pA[i] = g_Lb + (size_t)(m0 + row) * NR + kb + ((p ^ (row & 7)) << 3);
  }
  const unsigned short* pB[4];
#pragma unroll
  for (int i = 0; i < 4; i++) {
    int U = (wave * 4 + i) * 64 + lane;   // 0..1023
    int n = U >> 3, p = U & 7;
    pB[i] = BT + (size_t)n * NR + kb + ((p ^ (n & 7)) << 3);
  }

  float4_t acc[8];
#pragma unroll
  for (int ni = 0; ni < 8; ni++) acc[ni] = (float4_t){0.f, 0.f, 0.f, 0.f};

  for (int step = 0; step < KCHUNK / BK; step++) {
#pragma unroll
    for (int i = 0; i < 2; i++)
      gload_lds16(pA[i], (char*)As + (wave * 2 + i) * 1024);
#pragma unroll
    for (int i = 0; i < 4; i++)
      gload_lds16(pB[i], (char*)Bs + (wave * 4 + i) * 1024);
    __syncthreads();
#pragma unroll
    for (int ki = 0; ki < 2; ki++) {
      int row = wave * 16 + l15;
      int pa = ((ki << 2) | lq) ^ (row & 7);
      short8 a = *(const short8*)(As + row * 64 + pa * 8);
#pragma unroll
      for (int ni = 0; ni < 8; ni++) {
        int n = ni * 16 + l15;
        int pb = ((ki << 2) | lq) ^ (n & 7);
        short8 b = *(const short8*)(Bs + n * 64 + pb * 8);
        acc[ni] = __builtin_amdgcn_mfma_f32_16x16x32_bf16(a, b, acc[ni], 0, 0, 0);
      }
    }
    __syncthreads();
#pragma unroll
    for (int i = 0; i < 2; i++) pA[i] += BK;
#pragma unroll
    for (int i = 0; i < 4; i++) pB[i] += BK;
  }

  float* po = g_part + (size_t)blockIdx.y * NR * C;
#pragma unroll
  for (int ni = 0; ni < 8; ni++)
#pragma unroll
    for (int r = 0; r < 4; r++)
      po[(size_t)(m0 + wave * 16 + lq * 4 + r) * C + ni * 16 + l15] = acc[ni][r];
}

// ---- reduce split-K partials -> T1 bf16 (row-major + transposed) ------------
__global__ void reduce_t1() {
  __shared__ unsigned short tile[16][132];
  int r0 = blockIdx.x * 16;
  int t = threadIdx.x;
#pragma unroll
  for (int e = 0; e < 2; e++) {
    int linear = e * 1024 + t * 4;
    int r = linear >> 7, c = linear & 127;
    float4_t s = (float4_t){0.f, 0.f, 0.f, 0.f};
#pragma unroll
    for (int p = 0; p < SPLITK; p++)
      s += *(const float4_t*)(g_part + (size_t)p * NR * C + (size_t)(r0 + r) * C + c);
    ushort4_t h; h[0]=f2bf(s[0]); h[1]=f2bf(s[1]); h[2]=f2bf(s[2]); h[3]=f2bf(s[3]);
    *(ushort4_t*)(g_T1b + (size_t)(r0 + r) * C + c) = h;
    *(ushort4_t*)(&tile[r][c]) = h;
  }
  __syncthreads();
  int c = t >> 1, half = t & 1;
  unsigned short* dst = g_T1bT + (size_t)c * NR + r0 + half * 8;
#pragma unroll
  for (int seg = 0; seg < 2; seg++) {
    ushort4_t h;
#pragma unroll
    for (int j = 0; j < 4; j++) h[j] = tile[half * 8 + seg * 4 + j][c];
    *(ushort4_t*)(dst + seg * 4) = h;
  }
}

// ---- epilogue: reduce U partials, T2 = 2U - x, out = sum_j T_j W_j^T --------
__global__ __launch_bounds__(256) void epilogue(const float* __restrict__ x,
                                                float* __restrict__ out) {
  __shared__ unsigned short t2[32][136];
  int r0 = blockIdx.x * 32;
  int t = threadIdx.x;
#pragma unroll
  for (int e = 0; e < 4; e++) {
    int linear = e * 1024 + t * 4;
    int r = linear >> 7, c = linear & 127;
    float4_t s = (float4_t){0.f, 0.f, 0.f, 0.f};
#pragma unroll
    for (int p = 0; p < SPLITK; p++)
      s += *(const float4_t*)(g_part + (size_t)p * NR * C + (size_t)(r0 + r) * C + c);
    float4_t xv = *(const float4_t*)(x + (size_t)(r0 + r) * C + c);
    float4_t t2v = 2.0f * s - xv;
    ushort4_t h; h[0]=f2bf(t2v[0]); h[1]=f2bf(t2v[1]); h[2]=f2bf(t2v[2]); h[3]=f2bf(t2v[3]);
    *(ushort4_t*)(&t2[r][c]) = h;
  }
  __syncthreads();

  int wave = t >> 6, lane = t & 63, l15 = lane & 15, lq = lane >> 4;
  int mf = wave & 1, nh = wave >> 1;
  int m0r = r0 + mf * 16;
  float4_t acc[4];
#pragma unroll
  for (int ni = 0; ni < 4; ni++) acc[ni] = (float4_t){0.f, 0.f, 0.f, 0.f};

#pragma unroll
  for (int ks = 0; ks < 4; ks++) {
    int k0 = ks * 32 + lq * 8;
    const float* px = x + (size_t)(m0r + l15) * C + k0;
    float4_t f0 = *(const float4_t*)px;
    float4_t f1 = *(const float4_t*)(px + 4);
    short8 a0 = cvt8(f0, f1);
    short8 a1 = *(const short8*)(g_T1b + (size_t)(m0r + l15) * C + k0);
    short8 a2 = *(const short8*)(&t2[mf * 16 + l15][k0]);
#pragma unroll
    for (int ni = 0; ni < 4; ni++) {
      int n = nh * 64 + ni * 16 + l15;
      const unsigned short* pw = g_Wb + (size_t)n * C + k0;
      short8 w0 = *(const short8*)(pw);
      short8 w1 = *(const short8*)(pw + C * C);
      short8 w2 = *(const short8*)(pw + 2 * C * C);
      acc[ni] = __builtin_amdgcn_mfma_f32_16x16x32_bf16(a0, w0, acc[ni], 0, 0, 0);
      acc[ni] = __builtin_amdgcn_mfma_f32_16x16x32_bf16(a1, w1, acc[ni], 0, 0, 0);
      acc[ni] = __builtin_amdgcn_mfma_f32_16x16x32_bf16(a2, w2, acc[ni], 0, 0, 0);
    }
  }
#pragma unroll
  for (int ni = 0; ni < 4; ni++)
#pragma unroll
    for (int r = 0; r < 4; r++)
      out[(size_t)(m0r + lq * 4 + r) * C + nh * 64 + ni * 16 + l15] = acc[ni][r];
}

extern "C" void kernel_launch(void* const* d_in, const int* in_sizes, int n_in,
                              void* d_out, int out_size, void* d_ws, size_t ws_size,
                              hipStream_t stream) {
  const float* x = (const float*)d_in[0];   // [8192][128]
  const float* L = (const float*)d_in[1];   // [8192][8192]
  const float* W = (const float*)d_in[2];   // [3][128][128]
  float* out = (float*)d_out;               // [8192][128]

  cvt_w<<<48, 256, 0, stream>>>(W);
  transpose_x<<<dim3(128, 2), 256, 0, stream>>>(x);
  cvt_L<<<32768, 256, 0, stream>>>(L);              // L fp32 -> bf16 (streaming)
  gemm_bf16<<<dim3(128, SPLITK), 256, 0, stream>>>(0);   // T1 partials
  reduce_t1<<<512, 256, 0, stream>>>();                  // -> T1b, T1bT
  gemm_bf16<<<dim3(128, SPLITK), 256, 0, stream>>>(1);   // U partials
  epilogue<<<256, 256, 0, stream>>>(x, out);             // T2 + three W-GEMMs
}

// Round 4
// 508.050 us; speedup vs baseline: 1.2403x; 1.0028x over previous
//
#include <hip/hip_runtime.h>

typedef __attribute__((ext_vector_type(8))) short short8;
typedef __attribute__((ext_vector_type(4))) float float4_t;
typedef __attribute__((ext_vector_type(4))) unsigned short ushort4_t;

#define NR 8192
#define C 128
#define SPLITK 4
#define KCHUNK (NR / SPLITK)   // 2048
#define BK 64
#define STEPS (KCHUNK / BK)    // 32

// Static device scratch (fully rewritten each call; no reliance on ws_size).
__device__ unsigned short g_xbT[(size_t)C * NR];    // xbT[c][n] = bf16(x[n][c])
__device__ unsigned short g_T1b[(size_t)NR * C];    // row-major bf16 T1
__device__ unsigned short g_T1bT[(size_t)C * NR];   // T1bT[c][n] = bf16(T1[n][c])
__device__ unsigned short g_Wb[3 * C * C];          // bf16 W
__device__ float g_part[(size_t)SPLITK * NR * C];   // split-K partials (16 MB)

__device__ __forceinline__ unsigned short f2bf(float f) {
  union { float f; unsigned u; } v; v.f = f;
  unsigned r = v.u + 0x7fffu + ((v.u >> 16) & 1u);  // RNE
  return (unsigned short)(r >> 16);
}
__device__ __forceinline__ unsigned pk2(float a, float b) {
  union { float f; unsigned u; } x, y; x.f = a; y.f = b;
  unsigned ra = x.u + 0x7fffu + ((x.u >> 16) & 1u);
  unsigned rb = y.u + 0x7fffu + ((y.u >> 16) & 1u);
  return (ra >> 16) | (rb & 0xffff0000u);
}
__device__ __forceinline__ short8 cvt8(float4_t f0, float4_t f1) {
  union { unsigned u[4]; short8 s; } r;
  r.u[0] = pk2(f0[0], f0[1]); r.u[1] = pk2(f0[2], f0[3]);
  r.u[2] = pk2(f1[0], f1[1]); r.u[3] = pk2(f1[2], f1[3]);
  return r.s;
}

typedef __attribute__((address_space(3))) unsigned lds_uint;
typedef const __attribute__((address_space(1))) unsigned glob_uint;
__device__ __forceinline__ void gload_lds16(const void* g, void* l) {
  __builtin_amdgcn_global_load_lds((glob_uint*)g, (lds_uint*)l, 16, 0, 0);
}

// ---- tiny: W fp32 -> bf16 ---------------------------------------------------
__global__ void cvt_w(const float* __restrict__ W) {
  int i = (blockIdx.x * 256 + threadIdx.x) * 4;
  float4_t v = *(const float4_t*)(W + i);
  ushort4_t h; h[0]=f2bf(v[0]); h[1]=f2bf(v[1]); h[2]=f2bf(v[2]); h[3]=f2bf(v[3]);
  *(ushort4_t*)(g_Wb + i) = h;
}

// ---- x [8192][128] fp32 -> xbT [128][8192] bf16 -----------------------------
__global__ void transpose_x(const float* __restrict__ x) {
  __shared__ unsigned short xt[64][72];
  int r0 = blockIdx.x * 64;
  int c0 = blockIdx.y * 64;
  int t = threadIdx.x;
  int rr = t >> 4;
  int cc = (t & 15) * 4;
#pragma unroll
  for (int i = 0; i < 4; i++) {
    int row = i * 16 + rr;
    float4_t v = *(const float4_t*)(x + (size_t)(r0 + row) * C + c0 + cc);
    ushort4_t h; h[0]=f2bf(v[0]); h[1]=f2bf(v[1]); h[2]=f2bf(v[2]); h[3]=f2bf(v[3]);
    *(ushort4_t*)(&xt[row][cc]) = h;
  }
  __syncthreads();
  int c = t >> 2, q = t & 3;   // c 0..63, q: 16-row group
  unsigned short* dst = g_xbT + (size_t)(c0 + c) * NR + r0 + q * 16;
#pragma unroll
  for (int seg = 0; seg < 2; seg++) {
    short8 h;
#pragma unroll
    for (int j = 0; j < 8; j++) h[j] = (short)xt[q * 16 + seg * 8 + j][c];
    *(short8*)(dst + seg * 8) = h;   // 16B stores
  }
}

// ---- GEMM: part = L(fp32, cvt in-reg) @ B ; BM=64, BN=128, BK=64 ------------
// Double-buffered LDS, raw s_barrier + fine-grained vmcnt (no vmcnt(0) drain
// in steady state). which==0: BT=g_xbT (T1); which==1: BT=g_T1bT (U).
__global__ __launch_bounds__(256, 2) void gemm_cheb(const float* __restrict__ L, int which) {
  const unsigned short* __restrict__ BT = which ? g_T1bT : g_xbT;
  __shared__ __attribute__((aligned(16))) float          As[2][64 * BK];   // 2x16 KB
  __shared__ __attribute__((aligned(16))) unsigned short Bs[2][128 * BK];  // 2x16 KB
  int tid = threadIdx.x;
  int wave = tid >> 6, lane = tid & 63;
  int l15 = lane & 15, lq = lane >> 4;
  int m0 = blockIdx.x * 64;
  int kb = blockIdx.y * KCHUNK;

  // A staging: 64 rows x 64 fp32 = 16KB = 16 units of 16B per row.
  // physical unit p holds logical unit (p ^ (row&15)) -> conflict-free frags.
  const float* pA[4];
#pragma unroll
  for (int i = 0; i < 4; i++) {
    int U = (wave * 4 + i) * 64 + lane;   // 0..1023
    int row = U >> 4, p = U & 15;
    pA[i] = L + (size_t)(m0 + row) * NR + kb + ((p ^ (row & 15)) << 2);
  }
  // B staging: 128 n x 64 bf16 = 16KB = 8 units of 16B per row.
  const unsigned short* pB[4];
#pragma unroll
  for (int i = 0; i < 4; i++) {
    int U = (wave * 4 + i) * 64 + lane;   // 0..1023
    int n = U >> 3, p = U & 7;
    pB[i] = BT + (size_t)n * NR + kb + ((p ^ (n & 7)) << 3);
  }

  float4_t acc[8];
#pragma unroll
  for (int ni = 0; ni < 8; ni++) acc[ni] = (float4_t){0.f, 0.f, 0.f, 0.f};

  #define ISSUE(buf)                                                         \
    do {                                                                     \
      _Pragma("unroll")                                                      \
      for (int i = 0; i < 4; i++)                                            \
        gload_lds16(pA[i], (char*)&As[buf][0] + (wave * 4 + i) * 1024);      \
      _Pragma("unroll")                                                      \
      for (int i = 0; i < 4; i++)                                            \
        gload_lds16(pB[i], (char*)&Bs[buf][0] + (wave * 4 + i) * 1024);      \
      _Pragma("unroll")                                                      \
      for (int i = 0; i < 4; i++) { pA[i] += BK; pB[i] += BK; }              \
    } while (0)

  #define COMPUTE(buf)                                                       \
    do {                                                                     \
      _Pragma("unroll")                                                      \
      for (int ki = 0; ki < 2; ki++) {                                       \
        int row = wave * 16 + l15;                                           \
        int u0 = (ki << 3) | (lq << 1);                                      \
        int p0 = u0 ^ (row & 15);                                            \
        float4_t f0 = *(const float4_t*)((const char*)&As[buf][0] + row * 256 + p0 * 16);        \
        float4_t f1 = *(const float4_t*)((const char*)&As[buf][0] + row * 256 + (p0 ^ 1) * 16);  \
        short8 a = cvt8(f0, f1);                                             \
        _Pragma("unroll")                                                    \
        for (int ni = 0; ni < 8; ni++) {                                     \
          int n = ni * 16 + l15;                                             \
          int pb = ((ki << 2) | lq) ^ (n & 7);                               \
          short8 b = *(const short8*)((const char*)&Bs[buf][0] + n * 128 + pb * 16);             \
          acc[ni] = __builtin_amdgcn_mfma_f32_16x16x32_bf16(a, b, acc[ni], 0, 0, 0);             \
        }                                                                    \
      }                                                                      \
    } while (0)

  ISSUE(0);
  for (int step = 0; step < STEPS - 1; step++) {
    int p = step & 1;
    ISSUE(p ^ 1);                                        // prefetch step+1
    asm volatile("s_waitcnt vmcnt(8)" ::: "memory");     // my 8 loads for buf p done
    asm volatile("s_barrier" ::: "memory");              // everyone's are done
    COMPUTE(p);
    asm volatile("s_barrier" ::: "memory");              // buf p free to overwrite
  }
  asm volatile("s_waitcnt vmcnt(0)" ::: "memory");
  asm volatile("s_barrier" ::: "memory");
  COMPUTE((STEPS - 1) & 1);

  float* po = g_part + (size_t)blockIdx.y * NR * C;
#pragma unroll
  for (int ni = 0; ni < 8; ni++)
#pragma unroll
    for (int r = 0; r < 4; r++)
      po[(size_t)(m0 + wave * 16 + lq * 4 + r) * C + ni * 16 + l15] = acc[ni][r];
  #undef ISSUE
  #undef COMPUTE
}

// ---- reduce split-K partials -> T1 bf16 (row-major + transposed) ------------
__global__ void reduce_t1() {
  __shared__ unsigned short tile[16][136];
  int r0 = blockIdx.x * 16;
  int t = threadIdx.x;
#pragma unroll
  for (int e = 0; e < 2; e++) {
    int linear = e * 1024 + t * 4;
    int r = linear >> 7, c = linear & 127;
    float4_t s = (float4_t){0.f, 0.f, 0.f, 0.f};
#pragma unroll
    for (int p = 0; p < SPLITK; p++)
      s += *(const float4_t*)(g_part + (size_t)p * NR * C + (size_t)(r0 + r) * C + c);
    ushort4_t h; h[0]=f2bf(s[0]); h[1]=f2bf(s[1]); h[2]=f2bf(s[2]); h[3]=f2bf(s[3]);
    *(ushort4_t*)(g_T1b + (size_t)(r0 + r) * C + c) = h;
    *(ushort4_t*)(&tile[r][c]) = h;
  }
  __syncthreads();
  int c = t >> 1, half = t & 1;
  short8 h;
#pragma unroll
  for (int j = 0; j < 8; j++) h[j] = (short)tile[half * 8 + j][c];
  *(short8*)(g_T1bT + (size_t)c * NR + r0 + half * 8) = h;   // 16B store
}

// ---- epilogue: reduce U partials, T2 = 2U - x, out = sum_j T_j W_j^T --------
__global__ __launch_bounds__(256) void epilogue(const float* __restrict__ x,
                                                float* __restrict__ out) {
  __shared__ unsigned short t2[32][136];
  int r0 = blockIdx.x * 32;
  int t = threadIdx.x;
#pragma unroll
  for (int e = 0; e < 4; e++) {
    int linear = e * 1024 + t * 4;
    int r = linear >> 7, c = linear & 127;
    float4_t s = (float4_t){0.f, 0.f, 0.f, 0.f};
#pragma unroll
    for (int p = 0; p < SPLITK; p++)
      s += *(const float4_t*)(g_part + (size_t)p * NR * C + (size_t)(r0 + r) * C + c);
    float4_t xv = *(const float4_t*)(x + (size_t)(r0 + r) * C + c);
    float4_t t2v = 2.0f * s - xv;
    ushort4_t h; h[0]=f2bf(t2v[0]); h[1]=f2bf(t2v[1]); h[2]=f2bf(t2v[2]); h[3]=f2bf(t2v[3]);
    *(ushort4_t*)(&t2[r][c]) = h;
  }
  __syncthreads();

  int wave = t >> 6, lane = t & 63, l15 = lane & 15, lq = lane >> 4;
  int mf = wave & 1, nh = wave >> 1;
  int m0r = r0 + mf * 16;
  float4_t acc[4];
#pragma unroll
  for (int ni = 0; ni < 4; ni++) acc[ni] = (float4_t){0.f, 0.f, 0.f, 0.f};

#pragma unroll
  for (int ks = 0; ks < 4; ks++) {
    int k0 = ks * 32 + lq * 8;
    const float* px = x + (size_t)(m0r + l15) * C + k0;
    float4_t f0 = *(const float4_t*)px;
    float4_t f1 = *(const float4_t*)(px + 4);
    short8 a0 = cvt8(f0, f1);
    short8 a1 = *(const short8*)(g_T1b + (size_t)(m0r + l15) * C + k0);
    short8 a2 = *(const short8*)(&t2[mf * 16 + l15][k0]);
#pragma unroll
    for (int ni = 0; ni < 4; ni++) {
      int n = nh * 64 + ni * 16 + l15;
      const unsigned short* pw = g_Wb + (size_t)n * C + k0;
      short8 w0 = *(const short8*)(pw);
      short8 w1 = *(const short8*)(pw + C * C);
      short8 w2 = *(const short8*)(pw + 2 * C * C);
      acc[ni] = __builtin_amdgcn_mfma_f32_16x16x32_bf16(a0, w0, acc[ni], 0, 0, 0);
      acc[ni] = __builtin_amdgcn_mfma_f32_16x16x32_bf16(a1, w1, acc[ni], 0, 0, 0);
      acc[ni] = __builtin_amdgcn_mfma_f32_16x16x32_bf16(a2, w2, acc[ni], 0, 0, 0);
    }
  }
#pragma unroll
  for (int ni = 0; ni < 4; ni++)
#pragma unroll
    for (int r = 0; r < 4; r++)
      out[(size_t)(m0r + lq * 4 + r) * C + nh * 64 + ni * 16 + l15] = acc[ni][r];
}

extern "C" void kernel_launch(void* const* d_in, const int* in_sizes, int n_in,
                              void* d_out, int out_size, void* d_ws, size_t ws_size,
                              hipStream_t stream) {
  const float* x = (const float*)d_in[0];   // [8192][128]
  const float* L = (const float*)d_in[1];   // [8192][8192]
  const float* W = (const float*)d_in[2];   // [3][128][128]
  float* out = (float*)d_out;               // [8192][128]

  cvt_w<<<48, 256, 0, stream>>>(W);
  transpose_x<<<dim3(128, 2), 256, 0, stream>>>(x);
  gemm_cheb<<<dim3(128, SPLITK), 256, 0, stream>>>(L, 0);  // T1 partials
  reduce_t1<<<512, 256, 0, stream>>>();                    // -> T1b, T1bT
  gemm_cheb<<<dim3(128, SPLITK), 256, 0, stream>>>(L, 1);  // U partials
  epilogue<<<256, 256, 0, stream>>>(x, out);               // T2 + three W-GEMMs
}